// Round 2
// baseline (466.473 us; speedup 1.0000x reference)
//
#include <hip/hip_runtime.h>
#include <hip/hip_bf16.h>
#include <math.h>

#define T_TOK 32768
#define HD 1024
#define NE 8

typedef _Float16 half8 __attribute__((ext_vector_type(8)));
typedef _Float16 half4v __attribute__((ext_vector_type(4)));
typedef float f32x4 __attribute__((ext_vector_type(4)));

__device__ __forceinline__ void gload16(const void* g, void* l) {
  __builtin_amdgcn_global_load_lds((const __attribute__((address_space(1))) void*)g,
                                   (__attribute__((address_space(3))) void*)l,
                                   16, 0, 0);
}

// ---------------- router: logits, softmax, argmax, best_p ----------------
// one wave per token; fp64 accumulation to minimize argmax-tie risk vs JAX fp32
__global__ __launch_bounds__(256) void router_k(const float* __restrict__ x,
                                                const float* __restrict__ Wr,
                                                const float* __restrict__ br,
                                                int* __restrict__ best,
                                                float* __restrict__ bestp) {
  const int lane = threadIdx.x & 63;
  const int w = threadIdx.x >> 6;
  const int t = blockIdx.x * 4 + w;
  const float4* h4 = (const float4*)(x + (size_t)t * HD);
  const float4* wr4 = (const float4*)Wr;  // W_router [H][E] row-major, E=8 -> 2 float4 per k
  double p[NE];
#pragma unroll
  for (int e = 0; e < NE; ++e) p[e] = 0.0;
#pragma unroll
  for (int i = 0; i < 4; ++i) {
    const int k4 = lane + 64 * i;
    float4 v = h4[k4];
    float vv[4] = {v.x, v.y, v.z, v.w};
#pragma unroll
    for (int u = 0; u < 4; ++u) {
      const int k = k4 * 4 + u;
      float4 w0 = wr4[k * 2];
      float4 w1 = wr4[k * 2 + 1];
      double hv = (double)vv[u];
      p[0] += hv * (double)w0.x; p[1] += hv * (double)w0.y;
      p[2] += hv * (double)w0.z; p[3] += hv * (double)w0.w;
      p[4] += hv * (double)w1.x; p[5] += hv * (double)w1.y;
      p[6] += hv * (double)w1.z; p[7] += hv * (double)w1.w;
    }
  }
#pragma unroll
  for (int off = 32; off > 0; off >>= 1) {
#pragma unroll
    for (int e = 0; e < NE; ++e) p[e] += __shfl_xor(p[e], off);
  }
#pragma unroll
  for (int e = 0; e < NE; ++e) p[e] += (double)br[e];
  // argmax, first occurrence on ties (matches jnp.argmax)
  int be = 0; double bm = p[0];
#pragma unroll
  for (int e = 1; e < NE; ++e) if (p[e] > bm) { bm = p[e]; be = e; }
  double s = 0.0;
#pragma unroll
  for (int e = 0; e < NE; ++e) s += exp(p[e] - bm);
  if (lane == 0) { best[t] = be; bestp[t] = (float)(1.0 / s); }  // prob of best = 1/sum
}

// ---------------- stable counting sort: order = argsort(best) ----------------
// single block, 1024 threads x 32 tokens; stable => matches jnp.argsort (stable)
__global__ __launch_bounds__(1024) void sort_k(const int* __restrict__ best,
                                               int* __restrict__ order) {
  __shared__ int s[1024][NE];  // 32 KB
  const int i = threadIdx.x;
  int c[NE];
#pragma unroll
  for (int e = 0; e < NE; ++e) c[e] = 0;
  const int t0 = i * 32;
  for (int j = 0; j < 32; ++j) c[best[t0 + j]]++;
#pragma unroll
  for (int e = 0; e < NE; ++e) s[i][e] = c[e];
  __syncthreads();
  // Hillis-Steele inclusive scan over 1024 threads, 8 lanes wide
  for (int d = 1; d < 1024; d <<= 1) {
    int v[NE];
    if (i >= d) {
#pragma unroll
      for (int e = 0; e < NE; ++e) v[e] = s[i - d][e];
    }
    __syncthreads();
    if (i >= d) {
#pragma unroll
      for (int e = 0; e < NE; ++e) s[i][e] += v[e];
    }
    __syncthreads();
  }
  int basee[NE]; int a = 0;
#pragma unroll
  for (int e = 0; e < NE; ++e) { basee[e] = a; a += s[1023][e]; }  // expert bases
  int pos[NE];
#pragma unroll
  for (int e = 0; e < NE; ++e) pos[e] = basee[e] + s[i][e] - c[e];  // exclusive prefix
  for (int j = 0; j < 32; ++j) {
    int t = t0 + j;
    int e = best[t];
    order[pos[e]++] = t;
  }
}

// ---------------- W_expert fp32 [K][N] -> fp16 transposed [N][K] ----------------
__global__ __launch_bounds__(256) void wtrans_k(const float* __restrict__ W,
                                                _Float16* __restrict__ Wt) {
  __shared__ float tile[32][33];
  const int tx = threadIdx.x & 31, ty = threadIdx.x >> 5;  // ty 0..7
  const int kb = blockIdx.x * 32, nb = blockIdx.y * 32;
#pragma unroll
  for (int i = 0; i < 4; ++i)
    tile[ty + 8 * i][tx] = W[(size_t)(kb + ty + 8 * i) * HD + nb + tx];
  __syncthreads();
#pragma unroll
  for (int i = 0; i < 4; ++i)
    Wt[(size_t)(nb + ty + 8 * i) * HD + kb + tx] = (_Float16)tile[tx][ty + 8 * i];
}

// ---------------- gather permuted rows + convert fp32 -> fp16 ----------------
// one block per output row; A16[row] = fp16(h[order[row]])
__global__ __launch_bounds__(256) void gather_k(const float* __restrict__ x,
                                                const int* __restrict__ order,
                                                _Float16* __restrict__ A16) {
  const int row = blockIdx.x;
  const int src = order[row];
  const float4* in = (const float4*)(x + (size_t)src * HD);
  float4 v = in[threadIdx.x];
  half4v o = { (_Float16)v.x, (_Float16)v.y, (_Float16)v.z, (_Float16)v.w };
  ((half4v*)(A16 + (size_t)row * HD))[threadIdx.x] = o;
}

// ---------------- main GEMM: out[t] = (A16[t] @ W + b) * bestp[t] ----------------
// m97-structure: 128x128 tile, BK=32, width-16 global_load_lds, 4 waves, 4x4 acc
#define BM 128
#define BN 128
#define BK 32

__global__ __launch_bounds__(256) void gemm_k(const _Float16* __restrict__ A,
                                              const _Float16* __restrict__ Bt,
                                              const float* __restrict__ bias,
                                              const float* __restrict__ scale,
                                              float* __restrict__ out) {
  __shared__ alignas(16) _Float16 As[BM * BK];  // [m][k], 8 KB
  __shared__ alignas(16) _Float16 Bs[BN * BK];  // [n][k], 8 KB
  const int tid = threadIdx.x;
  const int w = tid >> 6, lane = tid & 63;
  const int wm = w >> 1, wn = w & 1;            // 2x2 wave grid, 64x64 per wave
  const int u = lane >> 4, r16 = lane & 15;
  const int mb = blockIdx.y, nb = blockIdx.x;
  const size_t abase = (size_t)mb * BM * HD;
  const size_t bbase = (size_t)nb * BN * HD;
  f32x4 acc[4][4];
#pragma unroll
  for (int m = 0; m < 4; ++m)
#pragma unroll
    for (int n = 0; n < 4; ++n) acc[m][n] = (f32x4){0.f, 0.f, 0.f, 0.f};

  for (int kt = 0; kt < HD / BK; ++kt) {
    __syncthreads();  // prior frag reads done before overwrite
#pragma unroll
    for (int i = 0; i < 2; ++i) {
      const int chunk = i * 4 + w;              // 8 x 1KB chunks per tile
      const int li = chunk * 64 + lane;         // 16B-unit index within tile
      const int row = li >> 2, col = li & 3;
      gload16(A + abase + (size_t)row * HD + kt * BK + col * 8, As + chunk * 512);
      gload16(Bt + bbase + (size_t)row * HD + kt * BK + col * 8, Bs + chunk * 512);
    }
    __syncthreads();  // compiler drains vmcnt before barrier -> LDS ready
    half8 af[4], bf[4];
#pragma unroll
    for (int m = 0; m < 4; ++m)
      af[m] = *(const half8*)(As + (wm * 64 + m * 16 + r16) * BK + u * 8);
#pragma unroll
    for (int n = 0; n < 4; ++n)
      bf[n] = *(const half8*)(Bs + (wn * 64 + n * 16 + r16) * BK + u * 8);
#pragma unroll
    for (int m = 0; m < 4; ++m)
#pragma unroll
      for (int n = 0; n < 4; ++n)
        acc[m][n] = __builtin_amdgcn_mfma_f32_16x16x32_f16(af[m], bf[n], acc[m][n], 0, 0, 0);
  }
  // epilogue: C/D layout col = lane&15, row = (lane>>4)*4 + reg (HW-verified m89/m91)
  const int colg0 = nb * BN + wn * 64 + r16;
  const int rowg0 = mb * BM + wm * 64 + u * 4;
  float bl[4];
#pragma unroll
  for (int n = 0; n < 4; ++n) bl[n] = bias[colg0 + n * 16];
#pragma unroll
  for (int m = 0; m < 4; ++m) {
#pragma unroll
    for (int j = 0; j < 4; ++j) {
      const int rowg = rowg0 + m * 16 + j;
      const float sc = scale[rowg];   // best_p indexed by POSITION (ref never unpermutes)
      float* op = out + (size_t)rowg * HD;
#pragma unroll
      for (int n = 0; n < 4; ++n)
        op[colg0 + n * 16] = (acc[m][n][j] + bl[n]) * sc;
    }
  }
}

extern "C" void kernel_launch(void* const* d_in, const int* in_sizes, int n_in,
                              void* d_out, int out_size, void* d_ws, size_t ws_size,
                              hipStream_t stream) {
  const float* x  = (const float*)d_in[0];
  const float* Wr = (const float*)d_in[1];
  const float* br = (const float*)d_in[2];
  const float* We = (const float*)d_in[3];
  const float* be = (const float*)d_in[4];
  float* out = (float*)d_out;

  // workspace layout (total ~66.5 MB)
  char* wsb = (char*)d_ws;
  int*      best  = (int*)wsb;                                  // 128 KB
  float*    bestp = (float*)(wsb + 131072);                     // 128 KB
  int*      order = (int*)(wsb + 262144);                       // 128 KB
  _Float16* Wt16  = (_Float16*)(wsb + 393216);                  // 2 MB
  _Float16* A16   = (_Float16*)(wsb + 393216 + 2097152);        // 64 MB

  hipLaunchKernelGGL(wtrans_k, dim3(32, 32), dim3(256), 0, stream, We, Wt16);
  hipLaunchKernelGGL(router_k, dim3(T_TOK / 4), dim3(256), 0, stream, x, Wr, br, best, bestp);
  hipLaunchKernelGGL(sort_k, dim3(1), dim3(1024), 0, stream, best, order);
  hipLaunchKernelGGL(gather_k, dim3(T_TOK), dim3(256), 0, stream, x, order, A16);
  hipLaunchKernelGGL(gemm_k, dim3(HD / BN, T_TOK / BM), dim3(256), 0, stream,
                     A16, Wt16, be, bestp, out);
}

// Round 3
// 452.921 us; speedup vs baseline: 1.0299x; 1.0299x over previous
//
#include <hip/hip_runtime.h>
#include <hip/hip_bf16.h>
#include <math.h>

#define T_TOK 32768
#define HD 1024
#define NE 8

typedef _Float16 half8 __attribute__((ext_vector_type(8)));
typedef _Float16 half4v __attribute__((ext_vector_type(4)));
typedef float f32x4 __attribute__((ext_vector_type(4)));

__device__ __forceinline__ void gload16(const void* g, void* l) {
  __builtin_amdgcn_global_load_lds((const __attribute__((address_space(1))) void*)g,
                                   (__attribute__((address_space(3))) void*)l,
                                   16, 0, 0);
}

// ---------------- router: fp64 dot (argmax-safe), parallel fp32 softmax tail ----
// wave per token. Dot stays fp64 (products of f32 are exact in f64; only the
// accumulation rounds) -> our argmax matches JAX-fp32 argmax unless jax's top-2
// gap < ~1e-13 (P ~ 3e-8 over the whole dataset).
__global__ __launch_bounds__(256) void router_k(const float* __restrict__ x,
                                                const float* __restrict__ Wr,
                                                const float* __restrict__ br,
                                                int* __restrict__ best,
                                                float* __restrict__ bestp) {
  const int lane = threadIdx.x & 63;
  const int w = threadIdx.x >> 6;
  const int t = blockIdx.x * 4 + w;
  const float4* h4 = (const float4*)(x + (size_t)t * HD);
  const float4* wr4 = (const float4*)Wr;  // W_router [H][E=8]: 2 float4 per k
  float4 xv[4];
#pragma unroll
  for (int i = 0; i < 4; ++i) xv[i] = h4[lane + 64 * i];  // hoisted, independent
  double p[NE] = {0, 0, 0, 0, 0, 0, 0, 0};
#pragma unroll
  for (int i = 0; i < 4; ++i) {
    float vv[4] = {xv[i].x, xv[i].y, xv[i].z, xv[i].w};
#pragma unroll
    for (int u = 0; u < 4; ++u) {
      const int k = (lane + 64 * i) * 4 + u;
      float4 w0 = wr4[k * 2];
      float4 w1 = wr4[k * 2 + 1];
      double hv = (double)vv[u];
      p[0] += hv * (double)w0.x; p[1] += hv * (double)w0.y;
      p[2] += hv * (double)w0.z; p[3] += hv * (double)w0.w;
      p[4] += hv * (double)w1.x; p[5] += hv * (double)w1.y;
      p[6] += hv * (double)w1.z; p[7] += hv * (double)w1.w;
    }
  }
  // 3 butterfly levels on all 8 -> each 8-lane subgroup holds subgroup sums
#pragma unroll
  for (int d = 1; d <= 4; d <<= 1)
#pragma unroll
    for (int e = 0; e < NE; ++e) p[e] += __shfl_xor(p[e], d);
  // lane keeps only expert (lane&7) via constant-index select tree
  const int el = lane & 7;
  double a0 = (el & 1) ? p[1] : p[0];
  double a1 = (el & 1) ? p[3] : p[2];
  double a2 = (el & 1) ? p[5] : p[4];
  double a3 = (el & 1) ? p[7] : p[6];
  double b0 = (el & 2) ? a1 : a0;
  double b1 = (el & 2) ? a3 : a2;
  double q  = (el & 4) ? b1 : b0;
  // finish the k-reduction across subgroups (single f64 now)
#pragma unroll
  for (int d = 8; d <= 32; d <<= 1) q += __shfl_xor(q, d);
  q += (double)br[el];
  // argmax over the 8 expert lanes (bits 0..2), first-wins on (f64-exact) ties
  double mq = q; int mi = el;
#pragma unroll
  for (int d = 1; d <= 4; d <<= 1) {
    double oq = __shfl_xor(mq, d);
    int    oi = __shfl_xor(mi, d);
    if (oq > mq || (oq == mq && oi < mi)) { mq = oq; mi = oi; }
  }
  // softmax denom in fp32 (bestp tolerance ~1e-7 rel; absmax budget is 1.6e-2)
  float ex = __expf((float)(q - mq));
#pragma unroll
  for (int d = 1; d <= 4; d <<= 1) ex += __shfl_xor(ex, d);
  if (lane == 0) { best[t] = mi; bestp[t] = 1.0f / ex; }  // prob of best = 1/sum
}

// ---------------- stable counting sort, 3 small kernels ----------------
// s1: per-block histogram (128 blocks x 256 tokens)
__global__ __launch_bounds__(256) void hist_k(const int* __restrict__ best,
                                              int* __restrict__ hist) {
  __shared__ int h[NE];
  if (threadIdx.x < NE) h[threadIdx.x] = 0;
  __syncthreads();
  const int t = blockIdx.x * 256 + threadIdx.x;
  atomicAdd(&h[best[t]], 1);
  __syncthreads();
  if (threadIdx.x < NE) hist[blockIdx.x * NE + threadIdx.x] = h[threadIdx.x];
}

// s2: offsets[b][e] = expertBase[e] + prefix_{b'<b}(hist[b'][e]); 1 block, 1024 thr
__global__ __launch_bounds__(1024) void scan_k(const int* __restrict__ hist,
                                               int* __restrict__ offs) {
  __shared__ int s[NE][129];
  __shared__ int ebase[NE];
  const int e = threadIdx.x >> 7, b = threadIdx.x & 127;
  const int v = hist[b * NE + e];
  s[e][b] = v;
  __syncthreads();
  for (int d = 1; d < 128; d <<= 1) {  // inclusive Hillis scan over blocks, per e
    int add = (b >= d) ? s[e][b - d] : 0;
    __syncthreads();
    s[e][b] += add;
    __syncthreads();
  }
  if (threadIdx.x == 0) {
    int a = 0;
#pragma unroll
    for (int ee = 0; ee < NE; ++ee) { ebase[ee] = a; a += s[ee][127]; }
  }
  __syncthreads();
  offs[b * NE + e] = ebase[e] + s[e][b] - v;  // exclusive prefix + expert base
}

// s3: stable scatter via wave ballots (block-major, wave-major, lane-major = token order)
__global__ __launch_bounds__(256) void scatter_k(const int* __restrict__ best,
                                                 const int* __restrict__ offs,
                                                 int* __restrict__ order) {
  __shared__ int whist[4][NE];
  const int tid = threadIdx.x, wv = tid >> 6, lane = tid & 63;
  const int t = blockIdx.x * 256 + tid;
  const int e = best[t];
  const unsigned long long lower = (lane == 63) ? ~0ull >> 1 : (1ull << lane) - 1;
  int myrank = 0;
#pragma unroll
  for (int E = 0; E < NE; ++E) {
    unsigned long long m = __ballot(e == E);
    if (e == E) myrank = __popcll(m & lower);
    if (lane == 0) whist[wv][E] = __popcll(m);
  }
  __syncthreads();
  int base = 0;
  for (int pw = 0; pw < wv; ++pw) base += whist[pw][e];
  order[offs[blockIdx.x * NE + e] + base + myrank] = t;
}

// ---------------- W_expert fp32 [K][N] -> fp16 transposed [N][K] ----------------
__global__ __launch_bounds__(256) void wtrans_k(const float* __restrict__ W,
                                                _Float16* __restrict__ Wt) {
  __shared__ float tile[32][33];
  const int tx = threadIdx.x & 31, ty = threadIdx.x >> 5;
  const int kb = blockIdx.x * 32, nb = blockIdx.y * 32;
#pragma unroll
  for (int i = 0; i < 4; ++i)
    tile[ty + 8 * i][tx] = W[(size_t)(kb + ty + 8 * i) * HD + nb + tx];
  __syncthreads();
#pragma unroll
  for (int i = 0; i < 4; ++i)
    Wt[(size_t)(nb + ty + 8 * i) * HD + kb + tx] = (_Float16)tile[tx][ty + 8 * i];
}

// ---------------- gather permuted rows + convert fp32 -> fp16 ----------------
__global__ __launch_bounds__(256) void gather_k(const float* __restrict__ x,
                                                const int* __restrict__ order,
                                                _Float16* __restrict__ A16) {
  const int row = blockIdx.x;
  const int src = order[row];
  const float4* in = (const float4*)(x + (size_t)src * HD);
  float4 v = in[threadIdx.x];
  half4v o = { (_Float16)v.x, (_Float16)v.y, (_Float16)v.z, (_Float16)v.w };
  ((half4v*)(A16 + (size_t)row * HD))[threadIdx.x] = o;
}

// ---------------- main GEMM: out[t] = (A16[t] @ W + b) * bestp[t] ----------------
// m97-structure (unchanged from passing round): 128x128, BK=32, gload_lds w16
#define BM 128
#define BN 128
#define BK 32

__global__ __launch_bounds__(256) void gemm_k(const _Float16* __restrict__ A,
                                              const _Float16* __restrict__ Bt,
                                              const float* __restrict__ bias,
                                              const float* __restrict__ scale,
                                              float* __restrict__ out) {
  __shared__ alignas(16) _Float16 As[BM * BK];
  __shared__ alignas(16) _Float16 Bs[BN * BK];
  const int tid = threadIdx.x;
  const int w = tid >> 6, lane = tid & 63;
  const int wm = w >> 1, wn = w & 1;
  const int u = lane >> 4, r16 = lane & 15;
  const int mb = blockIdx.y, nb = blockIdx.x;
  const size_t abase = (size_t)mb * BM * HD;
  const size_t bbase = (size_t)nb * BN * HD;
  f32x4 acc[4][4];
#pragma unroll
  for (int m = 0; m < 4; ++m)
#pragma unroll
    for (int n = 0; n < 4; ++n) acc[m][n] = (f32x4){0.f, 0.f, 0.f, 0.f};

  for (int kt = 0; kt < HD / BK; ++kt) {
    __syncthreads();
#pragma unroll
    for (int i = 0; i < 2; ++i) {
      const int chunk = i * 4 + w;
      const int li = chunk * 64 + lane;
      const int row = li >> 2, col = li & 3;
      gload16(A + abase + (size_t)row * HD + kt * BK + col * 8, As + chunk * 512);
      gload16(Bt + bbase + (size_t)row * HD + kt * BK + col * 8, Bs + chunk * 512);
    }
    __syncthreads();
    half8 af[4], bf[4];
#pragma unroll
    for (int m = 0; m < 4; ++m)
      af[m] = *(const half8*)(As + (wm * 64 + m * 16 + r16) * BK + u * 8);
#pragma unroll
    for (int n = 0; n < 4; ++n)
      bf[n] = *(const half8*)(Bs + (wn * 64 + n * 16 + r16) * BK + u * 8);
#pragma unroll
    for (int m = 0; m < 4; ++m)
#pragma unroll
      for (int n = 0; n < 4; ++n)
        acc[m][n] = __builtin_amdgcn_mfma_f32_16x16x32_f16(af[m], bf[n], acc[m][n], 0, 0, 0);
  }
  const int colg0 = nb * BN + wn * 64 + r16;
  const int rowg0 = mb * BM + wm * 64 + u * 4;
  float bl[4];
#pragma unroll
  for (int n = 0; n < 4; ++n) bl[n] = bias[colg0 + n * 16];
#pragma unroll
  for (int m = 0; m < 4; ++m) {
#pragma unroll
    for (int j = 0; j < 4; ++j) {
      const int rowg = rowg0 + m * 16 + j;
      const float sc = scale[rowg];  // best_p indexed by sorted POSITION (ref never unpermutes)
      float* op = out + (size_t)rowg * HD;
#pragma unroll
      for (int n = 0; n < 4; ++n)
        op[colg0 + n * 16] = (acc[m][n][j] + bl[n]) * sc;
    }
  }
}

extern "C" void kernel_launch(void* const* d_in, const int* in_sizes, int n_in,
                              void* d_out, int out_size, void* d_ws, size_t ws_size,
                              hipStream_t stream) {
  const float* x  = (const float*)d_in[0];
  const float* Wr = (const float*)d_in[1];
  const float* br = (const float*)d_in[2];
  const float* We = (const float*)d_in[3];
  const float* be = (const float*)d_in[4];
  float* out = (float*)d_out;

  char* wsb = (char*)d_ws;
  int*      best  = (int*)wsb;                                  // 128 KB
  float*    bestp = (float*)(wsb + 131072);                     // 128 KB
  int*      order = (int*)(wsb + 262144);                       // 128 KB
  int*      hist  = (int*)(wsb + 393216);                       // 4 KB
  int*      offs  = (int*)(wsb + 397312);                       // 4 KB
  _Float16* Wt16  = (_Float16*)(wsb + 401408);                  // 2 MB
  _Float16* A16   = (_Float16*)(wsb + 401408 + 2097152);        // 64 MB

  hipLaunchKernelGGL(wtrans_k, dim3(32, 32), dim3(256), 0, stream, We, Wt16);
  hipLaunchKernelGGL(router_k, dim3(T_TOK / 4), dim3(256), 0, stream, x, Wr, br, best, bestp);
  hipLaunchKernelGGL(hist_k, dim3(T_TOK / 256), dim3(256), 0, stream, best, hist);
  hipLaunchKernelGGL(scan_k, dim3(1), dim3(1024), 0, stream, hist, offs);
  hipLaunchKernelGGL(scatter_k, dim3(T_TOK / 256), dim3(256), 0, stream, best, offs, order);
  hipLaunchKernelGGL(gather_k, dim3(T_TOK), dim3(256), 0, stream, x, order, A16);
  hipLaunchKernelGGL(gemm_k, dim3(HD / BN, T_TOK / BM), dim3(256), 0, stream,
                     A16, Wt16, be, bestp, out);
}

// Round 5
// 386.131 us; speedup vs baseline: 1.2081x; 1.1730x over previous
//
#include <hip/hip_runtime.h>
#include <hip/hip_bf16.h>
#include <math.h>

#define T_TOK 32768
#define HD 1024
#define NE 8

typedef _Float16 half8 __attribute__((ext_vector_type(8)));
typedef _Float16 half4v __attribute__((ext_vector_type(4)));
typedef float f32x4 __attribute__((ext_vector_type(4)));

__device__ __forceinline__ void gload16(const void* g, void* l) {
  __builtin_amdgcn_global_load_lds((const __attribute__((address_space(1))) void*)g,
                                   (__attribute__((address_space(3))) void*)l,
                                   16, 0, 0);
}

// ---------------- router v3: coalesced W reads, 4 tokens/wave ----------------
// k = lane + 64*j  ->  consecutive lanes read consecutive 32B W rows (coalesced
// 2KB burst/iter) instead of 128B-stride scatter (was 64 cache lines per load
// instruction -> ~2K cycles/token L1 serialization, the round-3 bottleneck).
// f64 accumulation kept: products of f32 are exact in f64; reordering the sum
// moves logits ~1e-13 << dataset min top-2 gap (~1e-4 scale) -> argmax stable.
__global__ __launch_bounds__(256) void router_k(const float* __restrict__ x,
                                                const float* __restrict__ Wr,
                                                const float* __restrict__ br,
                                                int* __restrict__ best,
                                                float* __restrict__ bestp) {
  const int lane = threadIdx.x & 63;
  const int w = threadIdx.x >> 6;
  const int tbase = blockIdx.x * 16 + w * 4;   // 4 tokens per wave
  const float4* wr4 = (const float4*)Wr;       // W_router [H][E=8]: 2 float4 per row
  const float* x0 = x + (size_t)tbase * HD;
  double acc[4][NE];
#pragma unroll
  for (int t = 0; t < 4; ++t)
#pragma unroll
    for (int e = 0; e < NE; ++e) acc[t][e] = 0.0;

#pragma unroll 4
  for (int j = 0; j < 16; ++j) {
    const int k = lane + 64 * j;
    float4 w0 = wr4[k * 2];        // lanes stride 32B -> coalesced 2KB
    float4 w1 = wr4[k * 2 + 1];
    float xs[4];
#pragma unroll
    for (int t = 0; t < 4; ++t) xs[t] = x0[(size_t)t * HD + k];  // coalesced 256B
#pragma unroll
    for (int t = 0; t < 4; ++t) {
      double hv = (double)xs[t];
      acc[t][0] += hv * (double)w0.x; acc[t][1] += hv * (double)w0.y;
      acc[t][2] += hv * (double)w0.z; acc[t][3] += hv * (double)w0.w;
      acc[t][4] += hv * (double)w1.x; acc[t][5] += hv * (double)w1.y;
      acc[t][6] += hv * (double)w1.z; acc[t][7] += hv * (double)w1.w;
    }
  }

#pragma unroll
  for (int t = 0; t < 4; ++t) {
    double p[NE];
#pragma unroll
    for (int e = 0; e < NE; ++e) p[e] = acc[t][e];
    // 3 butterfly levels on all 8 -> each 8-lane subgroup holds subgroup sums
#pragma unroll
    for (int d = 1; d <= 4; d <<= 1)
#pragma unroll
      for (int e = 0; e < NE; ++e) p[e] += __shfl_xor(p[e], d);
    // lane keeps only expert (lane&7) via constant-index select tree
    const int el = lane & 7;
    double a0 = (el & 1) ? p[1] : p[0];
    double a1 = (el & 1) ? p[3] : p[2];
    double a2 = (el & 1) ? p[5] : p[4];
    double a3 = (el & 1) ? p[7] : p[6];
    double b0 = (el & 2) ? a1 : a0;
    double b1 = (el & 2) ? a3 : a2;
    double q  = (el & 4) ? b1 : b0;
    // finish k-reduction across subgroups (single f64 now)
#pragma unroll
    for (int d = 8; d <= 32; d <<= 1) q += __shfl_xor(q, d);
    q += (double)br[el];
    // argmax over the 8 expert lanes, first-wins on ties (matches jnp.argmax)
    double mq = q; int mi = el;
#pragma unroll
    for (int d = 1; d <= 4; d <<= 1) {
      double oq = __shfl_xor(mq, d);
      int    oi = __shfl_xor(mi, d);
      if (oq > mq || (oq == mq && oi < mi)) { mq = oq; mi = oi; }
    }
    // softmax denom in fp32 (bestp rel err ~1e-7; absmax budget is 1.6e-2)
    float ex = __expf((float)(q - mq));
#pragma unroll
    for (int d = 1; d <= 4; d <<= 1) ex += __shfl_xor(ex, d);
    if (lane == 0) { best[tbase + t] = mi; bestp[tbase + t] = 1.0f / ex; }
  }
}

// ---------------- stable counting sort, 3 small kernels (unchanged) ----------
__global__ __launch_bounds__(256) void hist_k(const int* __restrict__ best,
                                              int* __restrict__ hist) {
  __shared__ int h[NE];
  if (threadIdx.x < NE) h[threadIdx.x] = 0;
  __syncthreads();
  const int t = blockIdx.x * 256 + threadIdx.x;
  atomicAdd(&h[best[t]], 1);
  __syncthreads();
  if (threadIdx.x < NE) hist[blockIdx.x * NE + threadIdx.x] = h[threadIdx.x];
}

__global__ __launch_bounds__(1024) void scan_k(const int* __restrict__ hist,
                                               int* __restrict__ offs) {
  __shared__ int s[NE][129];
  __shared__ int ebase[NE];
  const int e = threadIdx.x >> 7, b = threadIdx.x & 127;
  const int v = hist[b * NE + e];
  s[e][b] = v;
  __syncthreads();
  for (int d = 1; d < 128; d <<= 1) {
    int add = (b >= d) ? s[e][b - d] : 0;
    __syncthreads();
    s[e][b] += add;
    __syncthreads();
  }
  if (threadIdx.x == 0) {
    int a = 0;
#pragma unroll
    for (int ee = 0; ee < NE; ++ee) { ebase[ee] = a; a += s[ee][127]; }
  }
  __syncthreads();
  offs[b * NE + e] = ebase[e] + s[e][b] - v;
}

__global__ __launch_bounds__(256) void scatter_k(const int* __restrict__ best,
                                                 const int* __restrict__ offs,
                                                 int* __restrict__ order) {
  __shared__ int whist[4][NE];
  const int tid = threadIdx.x, wv = tid >> 6, lane = tid & 63;
  const int t = blockIdx.x * 256 + tid;
  const int e = best[t];
  const unsigned long long lower = (lane == 63) ? ~0ull >> 1 : (1ull << lane) - 1;
  int myrank = 0;
#pragma unroll
  for (int E = 0; E < NE; ++E) {
    unsigned long long m = __ballot(e == E);
    if (e == E) myrank = __popcll(m & lower);
    if (lane == 0) whist[wv][E] = __popcll(m);
  }
  __syncthreads();
  int base = 0;
  for (int pw = 0; pw < wv; ++pw) base += whist[pw][e];
  order[offs[blockIdx.x * NE + e] + base + myrank] = t;
}

// ---------------- W_expert fp32 [K][N] -> fp16 transposed [N][K] (unchanged) --
__global__ __launch_bounds__(256) void wtrans_k(const float* __restrict__ W,
                                                _Float16* __restrict__ Wt) {
  __shared__ float tile[32][33];
  const int tx = threadIdx.x & 31, ty = threadIdx.x >> 5;
  const int kb = blockIdx.x * 32, nb = blockIdx.y * 32;
#pragma unroll
  for (int i = 0; i < 4; ++i)
    tile[ty + 8 * i][tx] = W[(size_t)(kb + ty + 8 * i) * HD + nb + tx];
  __syncthreads();
#pragma unroll
  for (int i = 0; i < 4; ++i)
    Wt[(size_t)(nb + ty + 8 * i) * HD + kb + tx] = (_Float16)tile[tx][ty + 8 * i];
}

// ---------------- gather permuted rows + convert fp32 -> fp16 (unchanged) ----
__global__ __launch_bounds__(256) void gather_k(const float* __restrict__ x,
                                                const int* __restrict__ order,
                                                _Float16* __restrict__ A16) {
  const int row = blockIdx.x;
  const int src = order[row];
  const float4* in = (const float4*)(x + (size_t)src * HD);
  float4 v = in[threadIdx.x];
  half4v o = { (_Float16)v.x, (_Float16)v.y, (_Float16)v.z, (_Float16)v.w };
  ((half4v*)(A16 + (size_t)row * HD))[threadIdx.x] = o;
}

// ---------------- main GEMM (unchanged, passing) ----------------
#define BM 128
#define BN 128
#define BK 32

__global__ __launch_bounds__(256) void gemm_k(const _Float16* __restrict__ A,
                                              const _Float16* __restrict__ Bt,
                                              const float* __restrict__ bias,
                                              const float* __restrict__ scale,
                                              float* __restrict__ out) {
  __shared__ alignas(16) _Float16 As[BM * BK];
  __shared__ alignas(16) _Float16 Bs[BN * BK];
  const int tid = threadIdx.x;
  const int w = tid >> 6, lane = tid & 63;
  const int wm = w >> 1, wn = w & 1;
  const int u = lane >> 4, r16 = lane & 15;
  const int mb = blockIdx.y, nb = blockIdx.x;
  const size_t abase = (size_t)mb * BM * HD;
  const size_t bbase = (size_t)nb * BN * HD;
  f32x4 acc[4][4];
#pragma unroll
  for (int m = 0; m < 4; ++m)
#pragma unroll
    for (int n = 0; n < 4; ++n) acc[m][n] = (f32x4){0.f, 0.f, 0.f, 0.f};

  for (int kt = 0; kt < HD / BK; ++kt) {
    __syncthreads();
#pragma unroll
    for (int i = 0; i < 2; ++i) {
      const int chunk = i * 4 + w;
      const int li = chunk * 64 + lane;
      const int row = li >> 2, col = li & 3;
      gload16(A + abase + (size_t)row * HD + kt * BK + col * 8, As + chunk * 512);
      gload16(Bt + bbase + (size_t)row * HD + kt * BK + col * 8, Bs + chunk * 512);
    }
    __syncthreads();
    half8 af[4], bf[4];
#pragma unroll
    for (int m = 0; m < 4; ++m)
      af[m] = *(const half8*)(As + (wm * 64 + m * 16 + r16) * BK + u * 8);
#pragma unroll
    for (int n = 0; n < 4; ++n)
      bf[n] = *(const half8*)(Bs + (wn * 64 + n * 16 + r16) * BK + u * 8);
#pragma unroll
    for (int m = 0; m < 4; ++m)
#pragma unroll
      for (int n = 0; n < 4; ++n)
        acc[m][n] = __builtin_amdgcn_mfma_f32_16x16x32_f16(af[m], bf[n], acc[m][n], 0, 0, 0);
  }
  const int colg0 = nb * BN + wn * 64 + r16;
  const int rowg0 = mb * BM + wm * 64 + u * 4;
  float bl[4];
#pragma unroll
  for (int n = 0; n < 4; ++n) bl[n] = bias[colg0 + n * 16];
#pragma unroll
  for (int m = 0; m < 4; ++m) {
#pragma unroll
    for (int j = 0; j < 4; ++j) {
      const int rowg = rowg0 + m * 16 + j;
      const float sc = scale[rowg];  // best_p indexed by sorted POSITION (ref never unpermutes)
      float* op = out + (size_t)rowg * HD;
#pragma unroll
      for (int n = 0; n < 4; ++n)
        op[colg0 + n * 16] = (acc[m][n][j] + bl[n]) * sc;
    }
  }
}

extern "C" void kernel_launch(void* const* d_in, const int* in_sizes, int n_in,
                              void* d_out, int out_size, void* d_ws, size_t ws_size,
                              hipStream_t stream) {
  const float* x  = (const float*)d_in[0];
  const float* Wr = (const float*)d_in[1];
  const float* br = (const float*)d_in[2];
  const float* We = (const float*)d_in[3];
  const float* be = (const float*)d_in[4];
  float* out = (float*)d_out;

  char* wsb = (char*)d_ws;
  int*      best  = (int*)wsb;                                  // 128 KB
  float*    bestp = (float*)(wsb + 131072);                     // 128 KB
  int*      order = (int*)(wsb + 262144);                       // 128 KB
  int*      hist  = (int*)(wsb + 393216);                       // 4 KB
  int*      offs  = (int*)(wsb + 397312);                       // 4 KB
  _Float16* Wt16  = (_Float16*)(wsb + 401408);                  // 2 MB
  _Float16* A16   = (_Float16*)(wsb + 401408 + 2097152);        // 64 MB

  hipLaunchKernelGGL(wtrans_k, dim3(32, 32), dim3(256), 0, stream, We, Wt16);
  hipLaunchKernelGGL(router_k, dim3(T_TOK / 16), dim3(256), 0, stream, x, Wr, br, best, bestp);
  hipLaunchKernelGGL(hist_k, dim3(T_TOK / 256), dim3(256), 0, stream, best, hist);
  hipLaunchKernelGGL(scan_k, dim3(1), dim3(1024), 0, stream, hist, offs);
  hipLaunchKernelGGL(scatter_k, dim3(T_TOK / 256), dim3(256), 0, stream, best, offs, order);
  hipLaunchKernelGGL(gather_k, dim3(T_TOK), dim3(256), 0, stream, x, order, A16);
  hipLaunchKernelGGL(gemm_k, dim3(HD / BN, T_TOK / BM), dim3(256), 0, stream,
                     A16, Wt16, be, bestp, out);
}